// Round 1
// baseline (520.260 us; speedup 1.0000x reference)
//
#include <hip/hip_runtime.h>
#include <stdint.h>

// Lorenz SDE, ShARK scheme. Streaming: read x[B,3], dW[B,5,3], dH[B,5,3] fp32,
// write yT[B,3]. 576 MB logical traffic -> HBM-bound roofline ~90 us (less with
// L3 retention).
//
// R2: same wave-autonomous tile structure as R1 (64 points/wave, private LDS
// slice, no __syncthreads), but staging now uses global_load_lds_dwordx4
// (direct HBM->LDS DMA). R1's VGPR round-trip staging was capped at ~2-3
// outstanding float4 loads by the 52-VGPR budget -> 3-4 serialized HBM
// latencies per wave -> 24% BW, VALUBusy 14% (latency-bound). Direct-to-LDS
// needs zero data VGPRs: all 9 staging ops issue back-to-back, one vmcnt(0)
// wait. LDS layout is already linear lane+k*64 float4 = the wave-uniform-base
// + lane*16B pattern the instruction writes (no padding anywhere).

#define NSTEPS 5
#define BLOCK 256
#define WPB 4          // waves per block
#define TILE 64        // points per wave

__device__ __forceinline__ void gll16(const float4* g, float* l) {
    __builtin_amdgcn_global_load_lds(
        (const __attribute__((address_space(1))) void*)g,
        (__attribute__((address_space(3))) void*)l,
        16, 0, 0);
}

__global__ __launch_bounds__(BLOCK) void lorenz_shark(
    const float* __restrict__ x,
    const float* __restrict__ dW,
    const float* __restrict__ dH,
    float* __restrict__ out)
{
    __shared__ float s_w[WPB][TILE * 15];   // 15 KB
    __shared__ float s_h[WPB][TILE * 15];   // 15 KB
    __shared__ float s_x[WPB][TILE * 3];    // 3 KB   (33 KB total, 4 blk/CU)

    const int lane = threadIdx.x & 63;
    const int wv   = threadIdx.x >> 6;
    const long long ptBase = ((long long)blockIdx.x * WPB + wv) * TILE;

    const float4* gw = (const float4*)(dW + ptBase * 15);   // 240 float4
    const float4* gh = (const float4*)(dH + ptBase * 15);   // 240 float4
    const float4* gx = (const float4*)(x  + ptBase * 3);    //  48 float4

    // ---- stage: direct global->LDS, all 9 dwordx4 DMAs in flight at once ----
#pragma unroll
    for (int k = 0; k < 3; ++k) {
        gll16(gw + lane + k * 64, &s_w[wv][k * 256]);
        gll16(gh + lane + k * 64, &s_h[wv][k * 256]);
    }
    if (lane < 48) {
        gll16(gw + lane + 192, &s_w[wv][768]);
        gll16(gh + lane + 192, &s_h[wv][768]);
        gll16(gx + lane,       &s_x[wv][0]);
    }
    asm volatile("s_waitcnt vmcnt(0)" ::: "memory");  // single drain: all 9 overlap
    __builtin_amdgcn_sched_barrier(0);
    __builtin_amdgcn_wave_barrier();   // pin compiler order: DMA writes before reads

    float a = s_x[wv][3 * lane + 0];
    float b = s_x[wv][3 * lane + 1];
    float c = s_x[wv][3 * lane + 2];

    const float cW    = 0.2f;                  // NOISE * sqrt(dt)
    const float cH    = 0.05773502691896258f;  // NOISE * sqrt(dt/12)
    const float dt    = 0.01f;
    const float c56   = 5.0f / 6.0f;
    const float c56dt = c56 * dt;
    const float SIGMA = 10.0f;
    const float RHO   = 28.0f;
    const float BETA  = 8.0f / 3.0f;

#pragma unroll
    for (int n = 0; n < NSTEPS; ++n) {
        const int w0 = 15 * lane + 3 * n;      // stride 15: 2 lanes/bank, free
        const float wa = s_w[wv][w0 + 0] * cW;
        const float wb = s_w[wv][w0 + 1] * cW;
        const float wc = s_w[wv][w0 + 2] * cW;
        const float ha = s_h[wv][w0 + 0] * cH;
        const float hb = s_h[wv][w0 + 1] * cH;
        const float hc = s_h[wv][w0 + 2] * cH;

        // z1 = y + h
        const float z1a = a + ha, z1b = b + hb, z1c = c + hc;
        const float f1a = SIGMA * (z1b - z1a);
        const float f1b = z1a * (RHO - z1c) - z1b;
        const float f1c = z1a * z1b - BETA * z1c;

        // z2 = y + (5/6)dt f1 + (5/6)w + h
        const float z2a = a + c56dt * f1a + c56 * wa + ha;
        const float z2b = b + c56dt * f1b + c56 * wb + hb;
        const float z2c = c + c56dt * f1c + c56 * wc + hc;
        const float f2a = SIGMA * (z2b - z2a);
        const float f2b = z2a * (RHO - z2c) - z2b;
        const float f2c = z2a * z2b - BETA * z2c;

        // y1 = y + dt(0.4 f1 + 0.6 f2) + w
        a = a + dt * (0.4f * f1a + 0.6f * f2a) + wa;
        b = b + dt * (0.4f * f1b + 0.6f * f2b) + wb;
        c = c + dt * (0.4f * f1c + 0.6f * f2c) + wc;
    }

    // result -> LDS slice -> coalesced float4 store (intra-wave, no barrier)
    s_x[wv][3 * lane + 0] = a;
    s_x[wv][3 * lane + 1] = b;
    s_x[wv][3 * lane + 2] = c;
    __builtin_amdgcn_wave_barrier();

    float4* lx = (float4*)s_x[wv];
    float4* go = (float4*)(out + ptBase * 3);
    if (lane < 48) go[lane] = lx[lane];
}

extern "C" void kernel_launch(void* const* d_in, const int* in_sizes, int n_in,
                              void* d_out, int out_size, void* d_ws, size_t ws_size,
                              hipStream_t stream) {
    const float* x  = (const float*)d_in[0];
    const float* dW = (const float*)d_in[1];
    const float* dH = (const float*)d_in[2];
    float* out = (float*)d_out;

    const int batch   = in_sizes[0] / 3;          // 4194304
    const int nblocks = batch / (WPB * TILE);     // 16384

    hipLaunchKernelGGL(lorenz_shark, dim3(nblocks), dim3(BLOCK), 0, stream,
                       x, dW, dH, out);
}